// Round 4
// baseline (7160.320 us; speedup 1.0000x reference)
//
#include <hip/hip_runtime.h>
#include <hip/hip_bf16.h>
#include <math.h>

#define B_ 64
#define N_ 100
#define C_ 92

// ---- bbox helpers (f32, fp-contract OFF to mirror strict numpy per-op IEEE) ----

__device__ __forceinline__ void cxcywh_to_xyxy(const float q[4], float o[4]) {
#pragma clang fp contract(off)
  float cx = q[0], cy = q[1], w = q[2], h = q[3];
  o[0] = cx - w * 0.5f;
  o[1] = cy - h * 0.5f;
  o[2] = cx + w * 0.5f;
  o[3] = cy + h * 0.5f;
}

__device__ __forceinline__ float pair_bbox_loss(const float* p, const float* t) {
#pragma clang fp contract(off)
  const float EPS = 1e-7f;
  float px1 = p[0], py1 = p[1], px2 = p[2], py2 = p[3];
  float tx1 = t[0], ty1 = t[1], tx2 = t[2], ty2 = t[3];
  float iw = fminf(px2, tx2) - fmaxf(px1, tx1); iw = fmaxf(iw, 0.0f);
  float ih = fminf(py2, ty2) - fmaxf(py1, ty1); ih = fmaxf(ih, 0.0f);
  float inter = iw * ih;
  float uni = (px2 - px1) * (py2 - py1) + (tx2 - tx1) * (ty2 - ty1) - inter;
  float iou = inter / (uni + EPS);
  float cw = fmaxf(px2, tx2) - fminf(px1, tx1);
  float ch = fmaxf(py2, ty2) - fminf(py1, ty1);
  float diag2 = cw * cw + ch * ch + EPS;
  float dx = (px1 + px2) * 0.5f - (tx1 + tx2) * 0.5f;
  float dy = (py1 + py2) * 0.5f - (ty1 + ty2) * 0.5f;
  float diou = 1.0f - iou + (dx * dx + dy * dy) / diag2;
  float s = 0.0f;
  for (int k = 0; k < 4; ++k) {
    float d = p[k] - t[k];
    float ad = fabsf(d);
    s += (ad < 1.0f) ? 0.5f * d * d : ad - 0.5f;
  }
  return diou + s * 0.25f;
}

// ---- Hungarian: one wave per batch; per-column state in LDS; f64 exact ----

__global__ __launch_bounds__(64) void hungarian_k(
    const int* __restrict__ targ_cat, const float* __restrict__ targ_bbox,
    const float* __restrict__ pred_cat, const float* __restrict__ pred_bbox,
    int* __restrict__ assign_ws, float* __restrict__ assign_out) {
  const int b = blockIdx.x;
  const int lane = threadIdx.x;

  __shared__ float costL[N_ * N_];   // [target_row][pred_col]
  __shared__ double u[N_ + 1];
  __shared__ double v[N_ + 1];
  __shared__ double minv[N_ + 1];
  __shared__ int way[N_ + 1];
  __shared__ int usedL[N_ + 1];
  __shared__ int p[N_ + 1];
  __shared__ double redV[64];
  __shared__ int redJ[64];
  __shared__ double deltaS;
  __shared__ int j1S;
  __shared__ float tb[N_ * 4];
  __shared__ float pbx[N_ * 4];
  __shared__ int tcat[N_];

  // stage boxes (xyxy) + categories
  for (int i = lane; i < N_; i += 64) {
    float q[4], o[4];
    q[0] = targ_bbox[(b * N_ + i) * 4 + 0];
    q[1] = targ_bbox[(b * N_ + i) * 4 + 1];
    q[2] = targ_bbox[(b * N_ + i) * 4 + 2];
    q[3] = targ_bbox[(b * N_ + i) * 4 + 3];
    cxcywh_to_xyxy(q, o);
    tb[i * 4 + 0] = o[0]; tb[i * 4 + 1] = o[1]; tb[i * 4 + 2] = o[2]; tb[i * 4 + 3] = o[3];
    q[0] = pred_bbox[(b * N_ + i) * 4 + 0];
    q[1] = pred_bbox[(b * N_ + i) * 4 + 1];
    q[2] = pred_bbox[(b * N_ + i) * 4 + 2];
    q[3] = pred_bbox[(b * N_ + i) * 4 + 3];
    cxcywh_to_xyxy(q, o);
    pbx[i * 4 + 0] = o[0]; pbx[i * 4 + 1] = o[1]; pbx[i * 4 + 2] = o[2]; pbx[i * 4 + 3] = o[3];
    tcat[i] = targ_cat[b * N_ + i];
  }
  __syncthreads();

  // cost[n][m] = -pred_cat[b,m,tc(n)] + (tc(n)==0) * pair_bbox_loss(pred m, targ n)
  for (int e = lane; e < N_ * N_; e += 64) {
    int n = e / N_;
    int m = e - n * N_;
    int tc = tcat[n];
    float cc = -pred_cat[(b * N_ + m) * C_ + tc];
    float pl = pair_bbox_loss(&pbx[m * 4], &tb[n * 4]);
    costL[e] = cc + ((tc == 0) ? pl : 0.0f);
  }
  for (int j = lane; j <= N_; j += 64) { u[j] = 0.0; v[j] = 0.0; p[j] = 0; }
  __syncthreads();

  const double INF = __builtin_huge_val();
  const int jA = lane + 1;              // cols 1..64
  const int jB = lane + 65;             // cols 65..100 (lanes 0..35)
  const bool hasB = (jB <= N_);

  for (int i = 1; i <= N_; ++i) {
    for (int j = lane; j <= N_; j += 64) { minv[j] = INF; usedL[j] = 0; way[j] = 0; }
    if (lane == 0) p[0] = i;
    int j0 = 0;                         // uniform
    int it = 0;

    while (true) {
      if (lane == 0) usedL[j0] = 1;
      __syncthreads();                  // usedL[j0], p[0], phase-init visible

      int i0 = p[j0];                   // uniform
      double ui = u[i0];                // uniform

      if (!usedL[jA]) {
        double cur = (double)costL[(i0 - 1) * N_ + (jA - 1)] - ui - v[jA];
        if (cur < minv[jA]) { minv[jA] = cur; way[jA] = j0; }
      }
      if (hasB && !usedL[jB]) {
        double cur = (double)costL[(i0 - 1) * N_ + (jB - 1)] - ui - v[jB];
        if (cur < minv[jB]) { minv[jB] = cur; way[jB] = j0; }
      }
      // per-lane candidate (jA before jB; strict < keeps lower index on tie)
      double cv = INF; int cj = N_ + 1;
      if (!usedL[jA]) { cv = minv[jA]; cj = jA; }
      if (hasB && !usedL[jB]) {
        double m2 = minv[jB];
        if (m2 < cv) { cv = m2; cj = jB; }
      }
      redV[lane] = cv; redJ[lane] = cj;
      __syncthreads();

      if (lane == 0) {
        double best = redV[0]; int bj = redJ[0];
        for (int l = 1; l < 64; ++l) {
          double v2 = redV[l]; int j2 = redJ[l];
          if (v2 < best || (v2 == best && j2 < bj)) { best = v2; bj = j2; }
        }
        deltaS = best; j1S = bj;
      }
      __syncthreads();

      double delta = deltaS;
      int j1 = j1S;
      if (j1 < 1 || j1 > N_) break;     // safety (unreachable for valid input)

      if (usedL[jA]) { v[jA] -= delta; u[p[jA]] += delta; }
      else           { minv[jA] -= delta; }
      if (hasB) {
        if (usedL[jB]) { v[jB] -= delta; u[p[jB]] += delta; }
        else           { minv[jB] -= delta; }
      }
      if (lane == 0) { v[0] -= delta; u[p[0]] += delta; }  // col 0 always used
      __syncthreads();

      j0 = j1;
      if (p[j0] == 0) break;
      if (++it > 2 * N_ + 4) break;     // safety net
    }

    if (lane == 0) {                    // augmenting-path reconstruction
      int jj = j0;
      while (jj != 0) { int jp = way[jj]; p[jj] = p[jp]; jj = jp; }
    }
    __syncthreads();
  }

  // ans[p[j]-1] = j-1  (float32 outputs)
  for (int j = lane + 1; j <= N_; j += 64) {
    int row = p[j] - 1;
    if (row < 0) row = 0;
    if (row >= N_) row = N_ - 1;
    assign_ws[b * N_ + row] = j - 1;
    assign_out[b * N_ + row] = (float)(j - 1);
  }
}

// ---- per-row losses: CE (log_softmax gather) + matched bbox pair loss ----

__global__ __launch_bounds__(256) void loss_rows_k(
    const int* __restrict__ targ_cat, const float* __restrict__ targ_bbox,
    const float* __restrict__ pred_cat, const float* __restrict__ pred_bbox,
    const int* __restrict__ assign,
    float* __restrict__ ce, float* __restrict__ lb, int* __restrict__ msk) {
  int t = blockIdx.x * blockDim.x + threadIdx.x;
  if (t >= B_ * N_) return;
  int b = t / N_;
  int m = assign[t];
  if (m < 0) m = 0;
  if (m >= N_) m = N_ - 1;
  int tc = targ_cat[t];

  const float* row = &pred_cat[(b * N_ + m) * C_];
  float mx = -INFINITY;
  for (int c = 0; c < C_; ++c) mx = fmaxf(mx, row[c]);
  float se = 0.0f;
  for (int c = 0; c < C_; ++c) se += expf(row[c] - mx);
  ce[t] = mx + logf(se) - row[tc];

  float q[4], po[4], to_[4];
  q[0] = pred_bbox[(b * N_ + m) * 4 + 0];
  q[1] = pred_bbox[(b * N_ + m) * 4 + 1];
  q[2] = pred_bbox[(b * N_ + m) * 4 + 2];
  q[3] = pred_bbox[(b * N_ + m) * 4 + 3];
  cxcywh_to_xyxy(q, po);
  q[0] = targ_bbox[t * 4 + 0];
  q[1] = targ_bbox[t * 4 + 1];
  q[2] = targ_bbox[t * 4 + 2];
  q[3] = targ_bbox[t * 4 + 3];
  cxcywh_to_xyxy(q, to_);
  float l = pair_bbox_loss(po, to_);
  bool mk = (tc != 0);
  lb[t] = mk ? l : 0.0f;
  msk[t] = mk ? 1 : 0;
}

// ---- deterministic final reduction -> float32 loss scalar ----

__global__ __launch_bounds__(256) void finalize_k(
    const float* __restrict__ ce, const float* __restrict__ lb,
    const int* __restrict__ msk, float* __restrict__ out) {
  __shared__ double s1[256];
  __shared__ double s2[256];
  __shared__ int s3[256];
  int tid = threadIdx.x;
  double a = 0.0, c2 = 0.0;
  int c3 = 0;
  for (int t = tid; t < B_ * N_; t += 256) {
    a += (double)ce[t]; c2 += (double)lb[t]; c3 += msk[t];
  }
  s1[tid] = a; s2[tid] = c2; s3[tid] = c3;
  __syncthreads();
  for (int off = 128; off > 0; off >>= 1) {
    if (tid < off) {
      s1[tid] += s1[tid + off]; s2[tid] += s2[tid + off]; s3[tid] += s3[tid + off];
    }
    __syncthreads();
  }
  if (tid == 0) {
    double loss = s1[0] / (double)(B_ * N_) + s2[0] / (double)s3[0];
    out[0] = (float)loss;
  }
}

extern "C" void kernel_launch(void* const* d_in, const int* in_sizes, int n_in,
                              void* d_out, int out_size, void* d_ws, size_t ws_size,
                              hipStream_t stream) {
  const int* targ_cat = (const int*)d_in[0];
  const float* targ_bbox = (const float*)d_in[1];
  const float* pred_cat = (const float*)d_in[2];
  const float* pred_bbox = (const float*)d_in[3];
  float* out = (float*)d_out;   // [0] = loss, [1..6400] = assign (as float32)

  char* ws = (char*)d_ws;
  int* assign_ws = (int*)(ws);             // 25.6 KB
  float* ce = (float*)(ws + (32 << 10));   // 25.6 KB
  float* lb = (float*)(ws + (64 << 10));   // 25.6 KB
  int* msk = (int*)(ws + (96 << 10));      // 25.6 KB  (total 128 KB)

  hipLaunchKernelGGL(hungarian_k, dim3(B_), dim3(64), 0, stream,
                     targ_cat, targ_bbox, pred_cat, pred_bbox, assign_ws, out + 1);
  hipLaunchKernelGGL(loss_rows_k, dim3((B_ * N_ + 255) / 256), dim3(256), 0, stream,
                     targ_cat, targ_bbox, pred_cat, pred_bbox, assign_ws, ce, lb, msk);
  hipLaunchKernelGGL(finalize_k, dim3(1), dim3(256), 0, stream, ce, lb, msk, out);
}

// Round 5
// 934.779 us; speedup vs baseline: 7.6599x; 7.6599x over previous
//
#include <hip/hip_runtime.h>
#include <hip/hip_bf16.h>
#include <math.h>

#define B_ 64
#define N_ 100
#define C_ 92

// ---- bbox helpers (f32, fp-contract OFF to mirror strict numpy per-op IEEE) ----

__device__ __forceinline__ void cxcywh_to_xyxy(const float q[4], float o[4]) {
#pragma clang fp contract(off)
  float cx = q[0], cy = q[1], w = q[2], h = q[3];
  o[0] = cx - w * 0.5f;
  o[1] = cy - h * 0.5f;
  o[2] = cx + w * 0.5f;
  o[3] = cy + h * 0.5f;
}

__device__ __forceinline__ float pair_bbox_loss(const float* p, const float* t) {
#pragma clang fp contract(off)
  const float EPS = 1e-7f;
  float px1 = p[0], py1 = p[1], px2 = p[2], py2 = p[3];
  float tx1 = t[0], ty1 = t[1], tx2 = t[2], ty2 = t[3];
  float iw = fminf(px2, tx2) - fmaxf(px1, tx1); iw = fmaxf(iw, 0.0f);
  float ih = fminf(py2, ty2) - fmaxf(py1, ty1); ih = fmaxf(ih, 0.0f);
  float inter = iw * ih;
  float uni = (px2 - px1) * (py2 - py1) + (tx2 - tx1) * (ty2 - ty1) - inter;
  float iou = inter / (uni + EPS);
  float cw = fmaxf(px2, tx2) - fminf(px1, tx1);
  float ch = fmaxf(py2, ty2) - fminf(py1, ty1);
  float diag2 = cw * cw + ch * ch + EPS;
  float dx = (px1 + px2) * 0.5f - (tx1 + tx2) * 0.5f;
  float dy = (py1 + py2) * 0.5f - (ty1 + ty2) * 0.5f;
  float diou = 1.0f - iou + (dx * dx + dy * dy) / diag2;
  float s = 0.0f;
  for (int k = 0; k < 4; ++k) {
    float d = p[k] - t[k];
    float ad = fabsf(d);
    s += (ad < 1.0f) ? 0.5f * d * d : ad - 0.5f;
  }
  return diou + s * 0.25f;
}

__device__ __forceinline__ int rdlane(int v, int srcLane) {
  return __builtin_amdgcn_readlane(v, srcLane);
}

// ---- Hungarian: one wave per batch. Register-distributed column state  ----
// ---- (2 cols/lane), shfl-butterfly f64 min + two-ballot argmin (exact  ----
// ---- np.argmin tie-break), u[] in LDS, p/way/v/minv in registers.      ----
// ---- Arithmetic trajectory is bit-identical to the numpy e-maxx loop.  ----

__global__ __launch_bounds__(64) void hungarian_k(
    const int* __restrict__ targ_cat, const float* __restrict__ targ_bbox,
    const float* __restrict__ pred_cat, const float* __restrict__ pred_bbox,
    int* __restrict__ assign_ws, float* __restrict__ assign_out) {
  const int b = blockIdx.x;
  const int lane = threadIdx.x;

  __shared__ float costL[N_ * N_];   // [target_row][pred_col]
  __shared__ double uL[N_ + 1];      // row potentials (rows 1..N)
  __shared__ float tb[N_ * 4];
  __shared__ float pbx[N_ * 4];
  __shared__ int tcat[N_];

  // stage boxes (xyxy) + categories
  for (int i = lane; i < N_; i += 64) {
    float q[4], o[4];
    q[0] = targ_bbox[(b * N_ + i) * 4 + 0];
    q[1] = targ_bbox[(b * N_ + i) * 4 + 1];
    q[2] = targ_bbox[(b * N_ + i) * 4 + 2];
    q[3] = targ_bbox[(b * N_ + i) * 4 + 3];
    cxcywh_to_xyxy(q, o);
    tb[i * 4 + 0] = o[0]; tb[i * 4 + 1] = o[1]; tb[i * 4 + 2] = o[2]; tb[i * 4 + 3] = o[3];
    q[0] = pred_bbox[(b * N_ + i) * 4 + 0];
    q[1] = pred_bbox[(b * N_ + i) * 4 + 1];
    q[2] = pred_bbox[(b * N_ + i) * 4 + 2];
    q[3] = pred_bbox[(b * N_ + i) * 4 + 3];
    cxcywh_to_xyxy(q, o);
    pbx[i * 4 + 0] = o[0]; pbx[i * 4 + 1] = o[1]; pbx[i * 4 + 2] = o[2]; pbx[i * 4 + 3] = o[3];
    tcat[i] = targ_cat[b * N_ + i];
  }
  __syncthreads();

  // cost[n][m] = -pred_cat[b,m,tc(n)] + (tc(n)==0) * pair_bbox_loss(pred m, targ n)
  for (int e = lane; e < N_ * N_; e += 64) {
    int n = e / N_;
    int m = e - n * N_;
    int tc = tcat[n];
    float cc = -pred_cat[(b * N_ + m) * C_ + tc];
    float pl = pair_bbox_loss(&pbx[m * 4], &tb[n * 4]);
    costL[e] = cc + ((tc == 0) ? pl : 0.0f);
  }
  for (int r = lane; r <= N_; r += 64) uL[r] = 0.0;
  __syncthreads();

  const double INF = __builtin_huge_val();
  const int jA = lane + 1;              // cols 1..64
  const int jB = lane + 65;             // cols 65..100 (lanes 0..35)
  const bool hasB = (jB <= N_);

  double vA = 0.0, vB = 0.0;            // column potentials (register)
  int pA = 0, pB = 0;                   // p[jA], p[jB]: matched row per column

  for (int i = 1; i <= N_; ++i) {
    double minvA = INF, minvB = INF;
    int wayA = 0, wayB = 0;
    bool usedA = false, usedB = false;
    int j0 = 0;
    int i0 = i;
    double ui0 = uL[i];                 // u[p[0]] at phase start (LDS broadcast)
    int it = 0;
    bool ok = true;

    while (true) {
      // used[j0] = true (first iteration: j0==0, no column marked)
      if (j0 == jA) usedA = true;
      if (hasB && j0 == jB) usedB = true;

      const float* crow = &costL[(i0 - 1) * N_];
      if (!usedA) {
        double cur = (double)crow[jA - 1] - ui0 - vA;
        if (cur < minvA) { minvA = cur; wayA = j0; }
      }
      if (hasB && !usedB) {
        double cur = (double)crow[jB - 1] - ui0 - vB;
        if (cur < minvB) { minvB = cur; wayB = j0; }
      }

      // global min over unused columns: f64 value butterfly (exact copies)
      double cvA = usedA ? INF : minvA;
      double cvB = (hasB && !usedB) ? minvB : INF;
      double m = fmin(cvA, cvB);
      m = fmin(m, __shfl_xor(m, 1));
      m = fmin(m, __shfl_xor(m, 2));
      m = fmin(m, __shfl_xor(m, 4));
      m = fmin(m, __shfl_xor(m, 8));
      m = fmin(m, __shfl_xor(m, 16));
      m = fmin(m, __shfl_xor(m, 32));
      if (m == INF) { ok = false; break; }   // unreachable for valid input

      // first-index argmin: A-range (cols 1..64) wins over B-range (65..100)
      unsigned long long mA = __ballot(cvA == m);
      int j1;
      if (mA) {
        j1 = __builtin_ctzll(mA) + 1;
      } else {
        unsigned long long mB = __ballot(cvB == m);
        if (!mB) { ok = false; break; }
        j1 = __builtin_ctzll(mB) + 65;
      }
      double delta = m;

      // used -> v -= delta, u[p[j]] += delta ; unused -> minv -= delta
      if (usedA) { vA -= delta; uL[pA] += delta; }
      else       { minvA -= delta; }
      if (hasB) {
        if (usedB) { vB -= delta; uL[pB] += delta; }
        else       { minvB -= delta; }
      }
      if (lane == 0) uL[i] += delta;    // column 0 (p[0]=i) is always used

      // p[j1] via readlane (uniform j1)
      int pj1 = (j1 <= 64) ? rdlane(pA, j1 - 1) : rdlane(pB, j1 - 65);
      j0 = j1;
      if (pj1 == 0) break;              // reached an unmatched column
      i0 = pj1;
      ui0 = uL[i0];                     // row i0 untouched this phase (proven)
      if (++it > 2 * N_ + 8) { ok = false; break; }
    }

    // augmenting-path reconstruction: uniform scalar walk over register state
    if (ok) {
      int jj = j0;
      int hop = 0;
      while (jj != 0 && ++hop <= N_ + 2) {
        int jp = (jj <= 64) ? rdlane(wayA, jj - 1) : rdlane(wayB, jj - 65);
        int pv = (jp == 0) ? i
                           : ((jp <= 64) ? rdlane(pA, jp - 1) : rdlane(pB, jp - 65));
        if (jj <= 64) { if (lane == jj - 1) pA = pv; }
        else          { if (lane == jj - 65) pB = pv; }
        jj = jp;
      }
    }
    __syncthreads();                    // order uL RMWs across phases (1 wave: cheap)
  }

  // ans[p[j]-1] = j-1  (float32 outputs)
  {
    int row = pA - 1;
    if (row < 0) row = 0;
    if (row >= N_) row = N_ - 1;
    assign_ws[b * N_ + row] = jA - 1;
    assign_out[b * N_ + row] = (float)(jA - 1);
    if (hasB) {
      int r2 = pB - 1;
      if (r2 < 0) r2 = 0;
      if (r2 >= N_) r2 = N_ - 1;
      assign_ws[b * N_ + r2] = jB - 1;
      assign_out[b * N_ + r2] = (float)(jB - 1);
    }
  }
}

// ---- per-row losses: CE (log_softmax gather) + matched bbox pair loss ----

__global__ __launch_bounds__(256) void loss_rows_k(
    const int* __restrict__ targ_cat, const float* __restrict__ targ_bbox,
    const float* __restrict__ pred_cat, const float* __restrict__ pred_bbox,
    const int* __restrict__ assign,
    float* __restrict__ ce, float* __restrict__ lb, int* __restrict__ msk) {
  int t = blockIdx.x * blockDim.x + threadIdx.x;
  if (t >= B_ * N_) return;
  int b = t / N_;
  int m = assign[t];
  if (m < 0) m = 0;
  if (m >= N_) m = N_ - 1;
  int tc = targ_cat[t];

  const float* row = &pred_cat[(b * N_ + m) * C_];
  float mx = -INFINITY;
  for (int c = 0; c < C_; ++c) mx = fmaxf(mx, row[c]);
  float se = 0.0f;
  for (int c = 0; c < C_; ++c) se += expf(row[c] - mx);
  ce[t] = mx + logf(se) - row[tc];

  float q[4], po[4], to_[4];
  q[0] = pred_bbox[(b * N_ + m) * 4 + 0];
  q[1] = pred_bbox[(b * N_ + m) * 4 + 1];
  q[2] = pred_bbox[(b * N_ + m) * 4 + 2];
  q[3] = pred_bbox[(b * N_ + m) * 4 + 3];
  cxcywh_to_xyxy(q, po);
  q[0] = targ_bbox[t * 4 + 0];
  q[1] = targ_bbox[t * 4 + 1];
  q[2] = targ_bbox[t * 4 + 2];
  q[3] = targ_bbox[t * 4 + 3];
  cxcywh_to_xyxy(q, to_);
  float l = pair_bbox_loss(po, to_);
  bool mk = (tc != 0);
  lb[t] = mk ? l : 0.0f;
  msk[t] = mk ? 1 : 0;
}

// ---- deterministic final reduction -> float32 loss scalar ----

__global__ __launch_bounds__(256) void finalize_k(
    const float* __restrict__ ce, const float* __restrict__ lb,
    const int* __restrict__ msk, float* __restrict__ out) {
  __shared__ double s1[256];
  __shared__ double s2[256];
  __shared__ int s3[256];
  int tid = threadIdx.x;
  double a = 0.0, c2 = 0.0;
  int c3 = 0;
  for (int t = tid; t < B_ * N_; t += 256) {
    a += (double)ce[t]; c2 += (double)lb[t]; c3 += msk[t];
  }
  s1[tid] = a; s2[tid] = c2; s3[tid] = c3;
  __syncthreads();
  for (int off = 128; off > 0; off >>= 1) {
    if (tid < off) {
      s1[tid] += s1[tid + off]; s2[tid] += s2[tid + off]; s3[tid] += s3[tid + off];
    }
    __syncthreads();
  }
  if (tid == 0) {
    double loss = s1[0] / (double)(B_ * N_) + s2[0] / (double)s3[0];
    out[0] = (float)loss;
  }
}

extern "C" void kernel_launch(void* const* d_in, const int* in_sizes, int n_in,
                              void* d_out, int out_size, void* d_ws, size_t ws_size,
                              hipStream_t stream) {
  const int* targ_cat = (const int*)d_in[0];
  const float* targ_bbox = (const float*)d_in[1];
  const float* pred_cat = (const float*)d_in[2];
  const float* pred_bbox = (const float*)d_in[3];
  float* out = (float*)d_out;   // [0] = loss, [1..6400] = assign (as float32)

  char* ws = (char*)d_ws;
  int* assign_ws = (int*)(ws);             // 25.6 KB
  float* ce = (float*)(ws + (32 << 10));   // 25.6 KB
  float* lb = (float*)(ws + (64 << 10));   // 25.6 KB
  int* msk = (int*)(ws + (96 << 10));      // 25.6 KB  (total 128 KB)

  hipLaunchKernelGGL(hungarian_k, dim3(B_), dim3(64), 0, stream,
                     targ_cat, targ_bbox, pred_cat, pred_bbox, assign_ws, out + 1);
  hipLaunchKernelGGL(loss_rows_k, dim3((B_ * N_ + 255) / 256), dim3(256), 0, stream,
                     targ_cat, targ_bbox, pred_cat, pred_bbox, assign_ws, ce, lb, msk);
  hipLaunchKernelGGL(finalize_k, dim3(1), dim3(256), 0, stream, ce, lb, msk, out);
}

// Round 6
// 597.629 us; speedup vs baseline: 11.9812x; 1.5641x over previous
//
#include <hip/hip_runtime.h>
#include <hip/hip_bf16.h>
#include <math.h>

#define B_ 64
#define N_ 100
#define C_ 92

// ---- bbox helpers (f32, fp-contract OFF to mirror strict numpy per-op IEEE) ----

__device__ __forceinline__ void cxcywh_to_xyxy(const float q[4], float o[4]) {
#pragma clang fp contract(off)
  float cx = q[0], cy = q[1], w = q[2], h = q[3];
  o[0] = cx - w * 0.5f;
  o[1] = cy - h * 0.5f;
  o[2] = cx + w * 0.5f;
  o[3] = cy + h * 0.5f;
}

__device__ __forceinline__ float pair_bbox_loss(const float* p, const float* t) {
#pragma clang fp contract(off)
  const float EPS = 1e-7f;
  float px1 = p[0], py1 = p[1], px2 = p[2], py2 = p[3];
  float tx1 = t[0], ty1 = t[1], tx2 = t[2], ty2 = t[3];
  float iw = fminf(px2, tx2) - fmaxf(px1, tx1); iw = fmaxf(iw, 0.0f);
  float ih = fminf(py2, ty2) - fmaxf(py1, ty1); ih = fmaxf(ih, 0.0f);
  float inter = iw * ih;
  float uni = (px2 - px1) * (py2 - py1) + (tx2 - tx1) * (ty2 - ty1) - inter;
  float iou = inter / (uni + EPS);
  float cw = fmaxf(px2, tx2) - fminf(px1, tx1);
  float ch = fmaxf(py2, ty2) - fminf(py1, ty1);
  float diag2 = cw * cw + ch * ch + EPS;
  float dx = (px1 + px2) * 0.5f - (tx1 + tx2) * 0.5f;
  float dy = (py1 + py2) * 0.5f - (ty1 + ty2) * 0.5f;
  float diou = 1.0f - iou + (dx * dx + dy * dy) / diag2;
  float s = 0.0f;
  for (int k = 0; k < 4; ++k) {
    float d = p[k] - t[k];
    float ad = fabsf(d);
    s += (ad < 1.0f) ? 0.5f * d * d : ad - 0.5f;
  }
  return diou + s * 0.25f;
}

__device__ __forceinline__ int rdlane(int v, int srcLane) {
  return __builtin_amdgcn_readlane(v, srcLane);
}

// DPP min step on f64: x = fmin(x, dpp_shuffled(x)); invalid lanes keep old
// (update_dpp old=own value, bound_ctrl=false) -> identity for min. Exact.
template <int CTRL>
__device__ __forceinline__ double dminstep(double x) {
  int lo = __double2loint(x), hi = __double2hiint(x);
  int slo = __builtin_amdgcn_update_dpp(lo, lo, CTRL, 0xF, 0xF, false);
  int shi = __builtin_amdgcn_update_dpp(hi, hi, CTRL, 0xF, 0xF, false);
  return fmin(x, __hiloint2double(shi, slo));
}

// read u[i0] from register-distributed rows (lane r-1 holds u[r], lane r-65 holds u[r] for r>=65)
__device__ __forceinline__ double read_u(double uA, double uB, int i0) {
  bool inA = (i0 <= 64);                 // i0 is wave-uniform
  double src = inA ? uA : uB;
  int idx = inA ? (i0 - 1) : (i0 - 65);
  int lo = rdlane(__double2loint(src), idx);
  int hi = rdlane(__double2hiint(src), idx);
  return __hiloint2double(hi, lo);
}

// ---- Hungarian: one wave per batch. ALL SAP state in registers         ----
// ---- (2 cols/lane: v,minv,way,p,used; 2 rows/lane: u + visited flag).  ----
// ---- DPP f64 min-reduce -> delta in SGPR; ballot argmin (np.argmin     ----
// ---- first-index tie-break). Cost matrix in LDS (read-only in loop).   ----
// ---- Arithmetic trajectory bit-identical to the numpy e-maxx loop.     ----

__global__ __launch_bounds__(64) void hungarian_k(
    const int* __restrict__ targ_cat, const float* __restrict__ targ_bbox,
    const float* __restrict__ pred_cat, const float* __restrict__ pred_bbox,
    int* __restrict__ assign_ws, float* __restrict__ assign_out) {
  const int b = blockIdx.x;
  const int lane = threadIdx.x;

  __shared__ float costL[N_ * N_];   // [target_row][pred_col]
  __shared__ float tb[N_ * 4];
  __shared__ float pbx[N_ * 4];
  __shared__ int tcat[N_];

  // stage boxes (xyxy) + categories
  for (int i = lane; i < N_; i += 64) {
    float q[4], o[4];
    q[0] = targ_bbox[(b * N_ + i) * 4 + 0];
    q[1] = targ_bbox[(b * N_ + i) * 4 + 1];
    q[2] = targ_bbox[(b * N_ + i) * 4 + 2];
    q[3] = targ_bbox[(b * N_ + i) * 4 + 3];
    cxcywh_to_xyxy(q, o);
    tb[i * 4 + 0] = o[0]; tb[i * 4 + 1] = o[1]; tb[i * 4 + 2] = o[2]; tb[i * 4 + 3] = o[3];
    q[0] = pred_bbox[(b * N_ + i) * 4 + 0];
    q[1] = pred_bbox[(b * N_ + i) * 4 + 1];
    q[2] = pred_bbox[(b * N_ + i) * 4 + 2];
    q[3] = pred_bbox[(b * N_ + i) * 4 + 3];
    cxcywh_to_xyxy(q, o);
    pbx[i * 4 + 0] = o[0]; pbx[i * 4 + 1] = o[1]; pbx[i * 4 + 2] = o[2]; pbx[i * 4 + 3] = o[3];
    tcat[i] = targ_cat[b * N_ + i];
  }
  __syncthreads();

  // cost[n][m] = -pred_cat[b,m,tc(n)] + (tc(n)==0) * pair_bbox_loss(pred m, targ n)
  for (int e = lane; e < N_ * N_; e += 64) {
    int n = e / N_;
    int m = e - n * N_;
    int tc = tcat[n];
    float cc = -pred_cat[(b * N_ + m) * C_ + tc];
    float pl = pair_bbox_loss(&pbx[m * 4], &tb[n * 4]);
    costL[e] = cc + ((tc == 0) ? pl : 0.0f);
  }
  __syncthreads();

  const double INF = __builtin_huge_val();
  const int jA = lane + 1;              // cols 1..64
  const int jB = lane + 65;             // cols 65..100 (lanes 0..35)
  const bool hasB = (jB <= N_);

  double vA = 0.0, vB = 0.0;            // column potentials
  double uA = 0.0, uB = 0.0;            // row potentials: u[lane+1], u[lane+65]
  int pA = 0, pB = 0;                   // matched row per column

  for (int i = 1; i <= N_; ++i) {
    double minvA = INF, minvB = INF;
    int wayA = 0, wayB = 0;
    bool usedA = false, usedB = false;
    bool fA = false, fB = false;        // row-visited flags (u receives deltas)
    int j0 = 0;
    int i0 = i;
    double ui0 = read_u(uA, uB, i0);
    float cA = costL[(i0 - 1) * N_ + (jA - 1)];
    float cB = 0.0f;
    if (hasB) cB = costL[(i0 - 1) * N_ + (jB - 1)];
    int it = 0;
    bool ok = true;

    while (true) {
      // mark used column j0 (first iter: j0==0, none); flag visited row i0
      if (j0 == jA) usedA = true;
      if (j0 == jB) usedB = true;
      fA = fA || (i0 == jA);            // row (lane+1) == i0
      fB = fB || (i0 == jB);            // row (lane+65) == i0

      if (!usedA) {
        double cur = (double)cA - ui0 - vA;
        if (cur < minvA) { minvA = cur; wayA = j0; }
      }
      if (hasB && !usedB) {
        double cur = (double)cB - ui0 - vB;
        if (cur < minvB) { minvB = cur; wayB = j0; }
      }

      // exact f64 min over unused columns: DPP reduce -> lane 63 -> SGPR
      double cvA = usedA ? INF : minvA;
      double cvB = (hasB && !usedB) ? minvB : INF;
      double r = fmin(cvA, cvB);
      r = dminstep<0x111>(r);           // row_shr:1
      r = dminstep<0x112>(r);           // row_shr:2
      r = dminstep<0x114>(r);           // row_shr:4
      r = dminstep<0x118>(r);           // row_shr:8  -> lane15 of each row = row min
      r = dminstep<0x142>(r);           // row_bcast15 -> lane31=min(r0,r1), lane63=min(r2,r3)
      r = dminstep<0x143>(r);           // row_bcast31 -> lane63 = global min
      double delta = __hiloint2double(rdlane(__double2hiint(r), 63),
                                      rdlane(__double2loint(r), 63));
      if (delta == INF) { ok = false; break; }   // unreachable for valid input

      // first-index argmin: A-range (cols 1..64) wins over B-range (65..100)
      unsigned long long mA = __ballot(cvA == delta);
      int j1;
      if (mA) {
        j1 = __builtin_ctzll(mA) + 1;
      } else {
        unsigned long long mB = __ballot(cvB == delta);
        if (!mB) { ok = false; break; }
        j1 = __builtin_ctzll(mB) + 65;
      }

      // next row + software-pipelined loads (issue before the update block)
      int pj1 = (j1 <= 64) ? rdlane(pA, j1 - 1) : rdlane(pB, j1 - 65);
      int ni0 = (pj1 == 0) ? 1 : pj1;   // dummy row if phase ends
      float nA = costL[(ni0 - 1) * N_ + (jA - 1)];
      float nB = 0.0f;
      if (hasB) nB = costL[(ni0 - 1) * N_ + (jB - 1)];
      double nui0 = read_u(uA, uB, ni0);  // row ni0 untouched this iteration (proven)

      // updates: visited rows u += delta; used cols v -= delta; else minv -= delta
      if (fA) uA += delta;
      if (fB) uB += delta;
      if (usedA) { vA -= delta; } else { minvA -= delta; }
      if (hasB) {
        if (usedB) { vB -= delta; } else { minvB -= delta; }
      }

      j0 = j1;
      if (pj1 == 0) break;              // reached an unmatched column
      i0 = ni0; ui0 = nui0; cA = nA; cB = nB;
      if (++it > 2 * N_ + 8) { ok = false; break; }
    }

    // augmenting-path reconstruction: uniform scalar walk over register state
    if (ok) {
      int jj = j0;
      int hop = 0;
      while (jj != 0 && ++hop <= N_ + 2) {
        int jp = (jj <= 64) ? rdlane(wayA, jj - 1) : rdlane(wayB, jj - 65);
        int pv = (jp == 0) ? i
                           : ((jp <= 64) ? rdlane(pA, jp - 1) : rdlane(pB, jp - 65));
        if (jj <= 64) { if (lane == jj - 1) pA = pv; }
        else          { if (lane == jj - 65) pB = pv; }
        jj = jp;
      }
    }
  }

  // ans[p[j]-1] = j-1  (float32 outputs)
  {
    int row = pA - 1;
    if (row < 0) row = 0;
    if (row >= N_) row = N_ - 1;
    assign_ws[b * N_ + row] = jA - 1;
    assign_out[b * N_ + row] = (float)(jA - 1);
    if (hasB) {
      int r2 = pB - 1;
      if (r2 < 0) r2 = 0;
      if (r2 >= N_) r2 = N_ - 1;
      assign_ws[b * N_ + r2] = jB - 1;
      assign_out[b * N_ + r2] = (float)(jB - 1);
    }
  }
}

// ---- per-row losses: CE (log_softmax gather) + matched bbox pair loss ----

__global__ __launch_bounds__(256) void loss_rows_k(
    const int* __restrict__ targ_cat, const float* __restrict__ targ_bbox,
    const float* __restrict__ pred_cat, const float* __restrict__ pred_bbox,
    const int* __restrict__ assign,
    float* __restrict__ ce, float* __restrict__ lb, int* __restrict__ msk) {
  int t = blockIdx.x * blockDim.x + threadIdx.x;
  if (t >= B_ * N_) return;
  int b = t / N_;
  int m = assign[t];
  if (m < 0) m = 0;
  if (m >= N_) m = N_ - 1;
  int tc = targ_cat[t];

  const float* row = &pred_cat[(b * N_ + m) * C_];
  float mx = -INFINITY;
  for (int c = 0; c < C_; ++c) mx = fmaxf(mx, row[c]);
  float se = 0.0f;
  for (int c = 0; c < C_; ++c) se += expf(row[c] - mx);
  ce[t] = mx + logf(se) - row[tc];

  float q[4], po[4], to_[4];
  q[0] = pred_bbox[(b * N_ + m) * 4 + 0];
  q[1] = pred_bbox[(b * N_ + m) * 4 + 1];
  q[2] = pred_bbox[(b * N_ + m) * 4 + 2];
  q[3] = pred_bbox[(b * N_ + m) * 4 + 3];
  cxcywh_to_xyxy(q, po);
  q[0] = targ_bbox[t * 4 + 0];
  q[1] = targ_bbox[t * 4 + 1];
  q[2] = targ_bbox[t * 4 + 2];
  q[3] = targ_bbox[t * 4 + 3];
  cxcywh_to_xyxy(q, to_);
  float l = pair_bbox_loss(po, to_);
  bool mk = (tc != 0);
  lb[t] = mk ? l : 0.0f;
  msk[t] = mk ? 1 : 0;
}

// ---- deterministic final reduction -> float32 loss scalar ----

__global__ __launch_bounds__(256) void finalize_k(
    const float* __restrict__ ce, const float* __restrict__ lb,
    const int* __restrict__ msk, float* __restrict__ out) {
  __shared__ double s1[256];
  __shared__ double s2[256];
  __shared__ int s3[256];
  int tid = threadIdx.x;
  double a = 0.0, c2 = 0.0;
  int c3 = 0;
  for (int t = tid; t < B_ * N_; t += 256) {
    a += (double)ce[t]; c2 += (double)lb[t]; c3 += msk[t];
  }
  s1[tid] = a; s2[tid] = c2; s3[tid] = c3;
  __syncthreads();
  for (int off = 128; off > 0; off >>= 1) {
    if (tid < off) {
      s1[tid] += s1[tid + off]; s2[tid] += s2[tid + off]; s3[tid] += s3[tid + off];
    }
    __syncthreads();
  }
  if (tid == 0) {
    double loss = s1[0] / (double)(B_ * N_) + s2[0] / (double)s3[0];
    out[0] = (float)loss;
  }
}

extern "C" void kernel_launch(void* const* d_in, const int* in_sizes, int n_in,
                              void* d_out, int out_size, void* d_ws, size_t ws_size,
                              hipStream_t stream) {
  const int* targ_cat = (const int*)d_in[0];
  const float* targ_bbox = (const float*)d_in[1];
  const float* pred_cat = (const float*)d_in[2];
  const float* pred_bbox = (const float*)d_in[3];
  float* out = (float*)d_out;   // [0] = loss, [1..6400] = assign (as float32)

  char* ws = (char*)d_ws;
  int* assign_ws = (int*)(ws);             // 25.6 KB
  float* ce = (float*)(ws + (32 << 10));   // 25.6 KB
  float* lb = (float*)(ws + (64 << 10));   // 25.6 KB
  int* msk = (int*)(ws + (96 << 10));      // 25.6 KB  (total 128 KB)

  hipLaunchKernelGGL(hungarian_k, dim3(B_), dim3(64), 0, stream,
                     targ_cat, targ_bbox, pred_cat, pred_bbox, assign_ws, out + 1);
  hipLaunchKernelGGL(loss_rows_k, dim3((B_ * N_ + 255) / 256), dim3(256), 0, stream,
                     targ_cat, targ_bbox, pred_cat, pred_bbox, assign_ws, ce, lb, msk);
  hipLaunchKernelGGL(finalize_k, dim3(1), dim3(256), 0, stream, ce, lb, msk, out);
}